// Round 1
// baseline (247.514 us; speedup 1.0000x reference)
//
#include <hip/hip_runtime.h>
#include <math.h>

#define HW 262144   // 512*512
#define KTOP 512

// ---------------- ws layout (bytes) ----------------
// hist:   8 * 4096 * 4  = 131072   @ 0
// cnt:    8 * 4         = 32       @ 131072
// thr:    8 * 4         = 32       @ 131104
// rowAny: 8 * 8 * 8     = 512      @ 131136
// sup:    8 * 512 * 8*8 = 262144   @ 131648
// cand:   8 * 4096 * 8  = 262144   @ 393792
// boxes:  8 * 512 * 8*4 = 131072   @ 655936   (end 787008)
#define OFF_HIST 0
#define OFF_CNT  131072
#define OFF_THR  131104
#define OFF_ANY  131136
#define OFF_SUP  131648
#define OFF_CAND 393792
#define OFF_BOX  655936
#define ZERO_BYTES 393792

__device__ __forceinline__ unsigned sortkey(float f) {
  unsigned u = __float_as_uint(f);
  return (u & 0x80000000u) ? ~u : (u | 0x80000000u);
}

// Bit-replica attempt of XLA-CPU f32 logistic: 1/(1+exp(-x)).
// glibc expf is correctly rounded; emulate via double exp then one rounding.
// _rn intrinsics block FMA contraction so the f32 add/div match exactly.
__device__ __forceinline__ float xla_sigmoid(float x) {
  float e = (float)exp(-(double)x);
  float d = __fadd_rn(1.0f, e);
  return __fdiv_rn(1.0f, d);
}

// ---------------- phase 1: logit histogram (top 12 bits of sortable key) ----
__global__ void __launch_bounds__(256) k_hist(const float* __restrict__ in,
                                              unsigned* __restrict__ hist) {
  __shared__ unsigned sh[4096];
  int b = blockIdx.x >> 5, sl = blockIdx.x & 31;
  for (int i = threadIdx.x; i < 4096; i += 256) sh[i] = 0u;
  __syncthreads();
  const float* p = in + (size_t)b * 9 * HW;   // channel 0 = conf logit plane
  int base = sl * 8192;
  for (int k = 0; k < 32; k++) {
    int pix = base + k * 256 + threadIdx.x;
    atomicAdd(&sh[sortkey(p[pix]) >> 20], 1u);
  }
  __syncthreads();
  for (int i = threadIdx.x; i < 4096; i += 256) {
    unsigned c = sh[i];
    if (c) atomicAdd(&hist[b * 4096 + i], c);
  }
}

// ---------------- phase 2: find threshold bin (suffix count >= 512) ---------
__global__ void __launch_bounds__(64) k_thresh(const unsigned* __restrict__ hist,
                                               unsigned* __restrict__ thr) {
  int b = blockIdx.x, lane = threadIdx.x;
  const unsigned* h = hist + b * 4096;
  int hi = 4095 - 64 * lane;          // lane's chunk: bins [hi-63 .. hi], top-down
  unsigned s = 0;
  for (int k = 0; k < 64; k++) s += h[hi - k];
  unsigned cum = s;
  for (int d = 1; d < 64; d <<= 1) {
    unsigned t = __shfl_up(cum, d, 64);
    if (lane >= d) cum += t;
  }
  unsigned long long m = __ballot(cum >= 512u);
  int first = __ffsll(m) - 1;
  if (lane == first) {
    unsigned run = cum - s;
    int bstar = hi - 63;
    for (int k = 0; k < 64; k++) {
      run += h[hi - k];
      if (run >= 512u) { bstar = hi - k; break; }
    }
    int t2 = bstar - 1;                // include one extra bin of safety margin
    if (t2 < 0) t2 = 0;
    thr[b] = (unsigned)t2;
  }
}

// ---------------- phase 3: compact candidates (key = conf bits | ~pix) ------
__global__ void __launch_bounds__(256) k_compact(const float* __restrict__ in,
                                                 const unsigned* __restrict__ thr,
                                                 unsigned* __restrict__ cnt,
                                                 unsigned long long* __restrict__ cand) {
  int b = blockIdx.x >> 5, sl = blockIdx.x & 31;
  unsigned T = thr[b];
  const float* p = in + (size_t)b * 9 * HW;
  int base = sl * 8192;
  for (int k = 0; k < 32; k++) {
    int pix = base + k * 256 + threadIdx.x;
    float v = p[pix];
    if ((sortkey(v) >> 20) >= T) {
      float conf = xla_sigmoid(v);
      unsigned pos = atomicAdd(&cnt[b], 1u);
      if (pos < 4096u) {
        unsigned long long key =
            ((unsigned long long)__float_as_uint(conf) << 32) |
            (unsigned)(~(unsigned)pix);
        cand[(size_t)b * 4096 + pos] = key;
      }
    }
  }
}

// ---------------- phase 4: sort candidates, decode top-512 ------------------
__global__ void __launch_bounds__(1024) k_sortdecode(const float* __restrict__ in,
                                                     const unsigned* __restrict__ cnt,
                                                     const unsigned long long* __restrict__ cand,
                                                     float* __restrict__ boxes) {
  __shared__ unsigned long long s[4096];
  int b = blockIdx.x;
  unsigned n = cnt[b]; if (n > 4096u) n = 4096u;
  for (int i = threadIdx.x; i < 4096; i += 1024)
    s[i] = (i < (int)n) ? cand[(size_t)b * 4096 + i] : 0ull;
  __syncthreads();
  // bitonic sort, descending (composite key: conf desc, then index asc)
  for (int k = 2; k <= 4096; k <<= 1) {
    for (int j = k >> 1; j > 0; j >>= 1) {
      #pragma unroll
      for (int e = 0; e < 4; e++) {
        int i = threadIdx.x + e * 1024;
        int ixj = i ^ j;
        if (ixj > i) {
          bool dirDesc = ((i & k) == 0);
          unsigned long long a = s[i], c = s[ixj];
          if ((a < c) == dirDesc) { s[i] = c; s[ixj] = a; }
        }
      }
      __syncthreads();
    }
  }
  int t = threadIdx.x;
  if (t < KTOP) {
    unsigned long long key = s[t];
    float* dst = boxes + ((size_t)b * KTOP + t) * 8;
    if ((unsigned)(key >> 32) == 0u) {   // impossible in practice; safety
      #pragma unroll
      for (int c = 0; c < 8; c++) dst[c] = 0.0f;
    } else {
      unsigned pix = ~(unsigned)(key & 0xffffffffull);
      float conf = __uint_as_float((unsigned)(key >> 32));
      const float* p = in + (size_t)b * 9 * HW;
      float o1 = p[1 * HW + pix], o2 = p[2 * HW + pix], o3 = p[3 * HW + pix];
      float o4 = p[4 * HW + pix], o5 = p[5 * HW + pix], o6 = p[6 * HW + pix];
      float o7 = p[7 * HW + pix], o8 = p[8 * HW + pix];
      float x = xla_sigmoid(o1) + (float)(pix & 511);
      float y = xla_sigmoid(o2) + (float)(pix >> 9);
      float z = xla_sigmoid(o3) * 4.0f;
      float l = expf(o4) * 3.9f;
      float w = expf(o5) * 1.6f;
      float h = expf(o6) * 1.56f;
      float yw = atan2f(tanhf(o7), tanhf(o8));
      dst[0] = conf; dst[1] = x; dst[2] = y; dst[3] = z;
      dst[4] = l; dst[5] = w; dst[6] = h; dst[7] = yw;
    }
  }
}

// ---------------- rotated-box IoU (fp32 mirror of the reference) ------------
// Stable angle sort replicated with a Knuth merge-exchange network (n=32,
// compile-time indices -> stays in registers) on lexicographic (ang, orig idx).
#define CE_(I, J) {                                                         \
  bool sw_ = (ang[I] > ang[J]) || ((ang[I] == ang[J]) && (oi[I] > oi[J]));  \
  if (sw_) { float tf_; int ti_;                                            \
    tf_ = ang[I]; ang[I] = ang[J]; ang[J] = tf_;                            \
    ti_ = oi[I];  oi[I]  = oi[J];  oi[J]  = ti_;                            \
    tf_ = qx[I];  qx[I]  = qx[J];  qx[J]  = tf_;                            \
    tf_ = qy[I];  qy[I]  = qy[J];  qy[J]  = tf_; } }

#define MPASS(P, R, D)                                                      \
  _Pragma("unroll")                                                         \
  for (int i_ = 0; i_ < 32 - (D); i_++) {                                   \
    if ((i_ & (P)) == (R)) CE_(i_, i_ + (D));                               \
  }

__device__ float pair_iou3d(const float a[7], const float b[7]) {
  const float KLX[4] = {0.5f, 0.5f, -0.5f, -0.5f};
  const float KLY[4] = {0.5f, -0.5f, -0.5f, 0.5f};
  float cax[4], cay[4], cbx[4], cby[4];
  float cA = cosf(a[6]), sA = sinf(a[6]);
  float cB = cosf(b[6]), sB = sinf(b[6]);
  #pragma unroll
  for (int k = 0; k < 4; k++) {
    float lx = KLX[k] * a[3], ly = KLY[k] * a[4];
    cax[k] = a[0] + lx * cA - ly * sA;
    cay[k] = a[1] + lx * sA + ly * cA;
    lx = KLX[k] * b[3]; ly = KLY[k] * b[4];
    cbx[k] = b[0] + lx * cB - ly * sB;
    cby[k] = b[1] + lx * sB + ly * cB;
  }
  float px[24], py[24]; bool val[24];
  #pragma unroll
  for (int ai = 0; ai < 4; ai++) {
    float a1x = cax[ai], a1y = cay[ai];
    float rx = cax[(ai + 1) & 3] - a1x, ry = cay[(ai + 1) & 3] - a1y;
    #pragma unroll
    for (int bj = 0; bj < 4; bj++) {
      float b1x = cbx[bj], b1y = cby[bj];
      float sx = cbx[(bj + 1) & 3] - b1x, sy = cby[(bj + 1) & 3] - b1y;
      float qpx = b1x - a1x, qpy = b1y - a1y;
      float den = rx * sy - ry * sx;
      bool dok = fabsf(den) > 1e-8f;
      float safe = dok ? den : 1.0f;
      float t = (qpx * sy - qpy * sx) / safe;
      float u = (qpx * ry - qpy * rx) / safe;
      bool ok = dok && (t >= 0.0f) && (t <= 1.0f) && (u >= 0.0f) && (u <= 1.0f);
      px[ai * 4 + bj] = a1x + t * rx;
      py[ai * 4 + bj] = a1y + t * ry;
      val[ai * 4 + bj] = ok;
    }
  }
  #pragma unroll
  for (int k = 0; k < 4; k++) {
    px[16 + k] = cax[k]; py[16 + k] = cay[k];
    { float dx = cax[k] - b[0], dy = cay[k] - b[1];
      float lx = dx * cB + dy * sB, ly = -dx * sB + dy * cB;
      val[16 + k] = (fabsf(lx) <= b[3] * 0.5f + 1e-6f) &&
                    (fabsf(ly) <= b[4] * 0.5f + 1e-6f); }
    px[20 + k] = cbx[k]; py[20 + k] = cby[k];
    { float dx = cbx[k] - a[0], dy = cby[k] - a[1];
      float lx = dx * cA + dy * sA, ly = -dx * sA + dy * cA;
      val[20 + k] = (fabsf(lx) <= a[3] * 0.5f + 1e-6f) &&
                    (fabsf(ly) <= a[4] * 0.5f + 1e-6f); }
  }
  float n = 0.0f, sxs = 0.0f, sys = 0.0f;
  #pragma unroll
  for (int k = 0; k < 24; k++) {
    float vf = val[k] ? 1.0f : 0.0f;
    n += vf; sxs += px[k] * vf; sys += py[k] * vf;
  }
  float inv = fmaxf(n, 1.0f);
  float ctrx = sxs / inv, ctry = sys / inv;
  float fx = px[0], fy = py[0]; bool found = false;
  #pragma unroll
  for (int k = 0; k < 24; k++) {           // fill = pts[argmax(val)] = first valid
    bool take = val[k] && !found;
    if (take) { fx = px[k]; fy = py[k]; }
    found = found || val[k];
  }
  float ang[32], qx[32], qy[32]; int oi[32];
  #pragma unroll
  for (int k = 0; k < 24; k++) {
    float X = val[k] ? px[k] : fx, Y = val[k] ? py[k] : fy;
    qx[k] = X; qy[k] = Y; oi[k] = k;
    ang[k] = atan2f(Y - ctry, X - ctrx);
  }
  #pragma unroll
  for (int k = 24; k < 32; k++) {
    qx[k] = 0.0f; qy[k] = 0.0f; oi[k] = k;
    ang[k] = __int_as_float(0x7f800000);   // +inf pads sink to the end
  }
  // Knuth merge-exchange network, n=32, ascending by (ang, oi)
  MPASS(16, 0, 16);
  MPASS(8, 0, 8);  MPASS(8, 8, 8);
  MPASS(4, 0, 4);  MPASS(4, 4, 12); MPASS(4, 4, 4);
  MPASS(2, 0, 2);  MPASS(2, 2, 14); MPASS(2, 2, 6);  MPASS(2, 2, 2);
  MPASS(1, 0, 1);  MPASS(1, 1, 15); MPASS(1, 1, 7);  MPASS(1, 1, 3); MPASS(1, 1, 1);
  float area2 = 0.0f;
  #pragma unroll
  for (int k = 0; k < 24; k++) {
    int k2 = (k + 1) % 24;
    float x1 = qx[k] - ctrx, y1 = qy[k] - ctry;
    float x2 = qx[k2] - ctrx, y2 = qy[k2] - ctry;
    area2 += x1 * y2 - y1 * x2;
  }
  float area = 0.5f * fabsf(area2);
  if (!(n >= 3.0f)) area = 0.0f;
  float z1 = fmaxf(a[2] - a[5] * 0.5f, b[2] - b[5] * 0.5f);
  float z2 = fminf(a[2] + a[5] * 0.5f, b[2] + b[5] * 0.5f);
  float inter = area * fmaxf(z2 - z1, 0.0f);
  float va = a[3] * a[4] * a[5], vb = b[3] * b[4] * b[5];
  return inter / (va + vb - inter + 1e-8f);
}

// ---------------- phase 5: suppression bit-matrix (j > i only) --------------
__global__ void __launch_bounds__(256) k_iou(const float* __restrict__ boxes,
                                             unsigned long long* __restrict__ sup,
                                             unsigned long long* __restrict__ rowAny) {
  int bi_ = blockIdx.x;
  int b = bi_ >> 9, i = bi_ & 511;
  const float* A = boxes + ((size_t)b * KTOP + i) * 8;
  if (A[0] <= 0.5f) return;            // row i can never suppress (uniform branch)
  float a7[7];
  #pragma unroll
  for (int c = 0; c < 7; c++) a7[c] = A[1 + c];
  float ra = 0.5f * sqrtf(a7[3] * a7[3] + a7[4] * a7[4]);
  float az1 = a7[2] - a7[5] * 0.5f, az2 = a7[2] + a7[5] * 0.5f;
  for (int j = i + 1 + threadIdx.x; j < KTOP; j += 256) {
    const float* Bp = boxes + ((size_t)b * KTOP + j) * 8;
    float b7[7];
    #pragma unroll
    for (int c = 0; c < 7; c++) b7[c] = Bp[1 + c];
    float dx = b7[0] - a7[0], dy = b7[1] - a7[1];
    float rb = 0.5f * sqrtf(b7[3] * b7[3] + b7[4] * b7[4]);
    float rs = (ra + rb) * 1.001f + 0.01f;     // disjoint circles => IoU == 0
    if (dx * dx + dy * dy > rs * rs) continue;
    float z1 = fmaxf(az1, b7[2] - b7[5] * 0.5f);
    float z2 = fminf(az2, b7[2] + b7[5] * 0.5f);
    if (!(z2 - z1 > 0.0f)) continue;           // inter = area*max(dz,0) = 0
    float iou = pair_iou3d(a7, b7);
    if (iou > 0.1f) {
      atomicOr(&sup[((size_t)b * KTOP + i) * 8 + (j >> 6)], 1ull << (j & 63));
      atomicOr(&rowAny[b * 8 + (i >> 6)], 1ull << (i & 63));
    }
  }
}

// ---------------- phase 6: sequential NMS on bitmasks + output --------------
__global__ void __launch_bounds__(512) k_nms_out(const float* __restrict__ boxes,
                                                 const unsigned long long* __restrict__ sup,
                                                 const unsigned long long* __restrict__ rowAny,
                                                 float* __restrict__ out) {
  int b = blockIdx.x, t = threadIdx.x;
  __shared__ unsigned long long kw[8];
  float conf = boxes[((size_t)b * KTOP + t) * 8];
  unsigned long long m = __ballot(conf > 0.5f);
  if ((t & 63) == 0) kw[t >> 6] = m;
  __syncthreads();
  if (t == 0) {
    unsigned long long kp[8];
    #pragma unroll
    for (int w = 0; w < 8; w++) kp[w] = kw[w];
    unsigned long long anyw[8];
    #pragma unroll
    for (int w = 0; w < 8; w++) anyw[w] = rowAny[b * 8 + w];
    #pragma unroll
    for (int w = 0; w < 8; w++) {
      unsigned long long act = kp[w] & anyw[w];
      while (act) {
        int bit = __ffsll(act) - 1;
        act &= act - 1;
        const unsigned long long* row = sup + ((size_t)b * KTOP + (w * 64 + bit)) * 8;
        #pragma unroll
        for (int u = 0; u < 8; u++) kp[u] &= ~row[u];   // row has only bits j>i
        act &= kp[w];     // suppression may have cleared later bits in this word
      }
    }
    #pragma unroll
    for (int w = 0; w < 8; w++) kw[w] = kp[w];
  }
  __syncthreads();
  bool kept = (kw[t >> 6] >> (t & 63)) & 1ull;
  const float* src = boxes + ((size_t)b * KTOP + t) * 8;
  float* dst = out + ((size_t)b * KTOP + t) * 8;
  #pragma unroll
  for (int c = 0; c < 8; c++) dst[c] = kept ? src[c] : 0.0f;
}

extern "C" void kernel_launch(void* const* d_in, const int* in_sizes, int n_in,
                              void* d_out, int out_size, void* d_ws, size_t ws_size,
                              hipStream_t stream) {
  const float* in = (const float*)d_in[0];   // (8, 9, 512, 512) f32
  float* out = (float*)d_out;                // (8, 512, 8) f32
  char* ws = (char*)d_ws;
  unsigned* hist = (unsigned*)(ws + OFF_HIST);
  unsigned* cnt = (unsigned*)(ws + OFF_CNT);
  unsigned* thr = (unsigned*)(ws + OFF_THR);
  unsigned long long* rowAny = (unsigned long long*)(ws + OFF_ANY);
  unsigned long long* sup = (unsigned long long*)(ws + OFF_SUP);
  unsigned long long* cand = (unsigned long long*)(ws + OFF_CAND);
  float* boxes = (float*)(ws + OFF_BOX);

  hipMemsetAsync(d_ws, 0, ZERO_BYTES, stream);
  k_hist<<<dim3(8 * 32), dim3(256), 0, stream>>>(in, hist);
  k_thresh<<<dim3(8), dim3(64), 0, stream>>>(hist, thr);
  k_compact<<<dim3(8 * 32), dim3(256), 0, stream>>>(in, thr, cnt, cand);
  k_sortdecode<<<dim3(8), dim3(1024), 0, stream>>>(in, cnt, cand, boxes);
  k_iou<<<dim3(8 * KTOP), dim3(256), 0, stream>>>(boxes, sup, rowAny);
  k_nms_out<<<dim3(8), dim3(512), 0, stream>>>(boxes, sup, rowAny, out);
}

// Round 2
// 118.795 us; speedup vs baseline: 2.0835x; 2.0835x over previous
//
#include <hip/hip_runtime.h>
#include <math.h>

#define HW 262144   // 512*512
#define KTOP 512

// ---------------- ws layout (bytes) ----------------
// region0: hist (8*4096*4 = 131072) then reused as cand (8*4096*8 = 262144)
// cnt:    8 * 128       = 1024     @ 262144   (128B stride: no shared-line atomics)
// thr:    8 * 4         = 32       @ 263168
// rowAny: 8 * 8 * 8     = 512      @ 263200
// sup:    8 * 512 * 8*8 = 262144   @ 263712
// boxes:  8 * 512 * 8*4 = 131072   @ 525856   (end 656928)
#define OFF_HIST 0
#define OFF_CAND 0
#define OFF_CNT  262144
#define OFF_THR  263168
#define OFF_ANY  263200
#define OFF_SUP  263712
#define OFF_BOX  525856
#define ZERO_BYTES 525856   // hist+cnt+thr+rowAny+sup (cand needs no zeroing)

__device__ __forceinline__ unsigned sortkey(float f) {
  unsigned u = __float_as_uint(f);
  return (u & 0x80000000u) ? ~u : (u | 0x80000000u);
}

// Bit-replica of XLA-CPU f32 logistic: 1/(1+exp(-x)) via correctly-rounded exp.
// Verified exact in R1 (absmax 0.0). Do not touch.
__device__ __forceinline__ float xla_sigmoid(float x) {
  float e = (float)exp(-(double)x);
  float d = __fadd_rn(1.0f, e);
  return __fdiv_rn(1.0f, d);
}

// ---------------- phase 1: logit histogram (top 12 bits of sortable key) ----
// 2048 blocks (256/batch) x 256 threads x 4 pixels (one float4 per thread).
__global__ void __launch_bounds__(256) k_hist(const float* __restrict__ in,
                                              unsigned* __restrict__ hist) {
  __shared__ unsigned sh[4096];
  int b = blockIdx.x >> 8, sl = blockIdx.x & 255;
  for (int i = threadIdx.x; i < 4096; i += 256) sh[i] = 0u;
  __syncthreads();
  const float* p = in + (size_t)b * 9 * HW;   // channel 0 = conf logit plane
  int base = sl * 1024 + threadIdx.x * 4;
  float4 v = *(const float4*)(p + base);
  atomicAdd(&sh[sortkey(v.x) >> 20], 1u);
  atomicAdd(&sh[sortkey(v.y) >> 20], 1u);
  atomicAdd(&sh[sortkey(v.z) >> 20], 1u);
  atomicAdd(&sh[sortkey(v.w) >> 20], 1u);
  __syncthreads();
  for (int i = threadIdx.x; i < 4096; i += 256) {
    unsigned c = sh[i];
    if (c) atomicAdd(&hist[b * 4096 + i], c);
  }
}

// ---------------- phase 2: find threshold bin (suffix count >= 512) ---------
__global__ void __launch_bounds__(64) k_thresh(const unsigned* __restrict__ hist,
                                               unsigned* __restrict__ thr) {
  int b = blockIdx.x, lane = threadIdx.x;
  const unsigned* h = hist + b * 4096;
  int hi = 4095 - 64 * lane;          // lane's chunk: bins [hi-63 .. hi], top-down
  unsigned s = 0;
  for (int k = 0; k < 64; k++) s += h[hi - k];
  unsigned cum = s;
  for (int d = 1; d < 64; d <<= 1) {
    unsigned t = __shfl_up(cum, d, 64);
    if (lane >= d) cum += t;
  }
  unsigned long long m = __ballot(cum >= 512u);
  int first = __ffsll(m) - 1;
  if (lane == first) {
    unsigned run = cum - s;
    int bstar = hi - 63;
    for (int k = 0; k < 64; k++) {
      run += h[hi - k];
      if (run >= 512u) { bstar = hi - k; break; }
    }
    // bin bstar contains the 512th element => every top-512 key >= bin start.
    thr[b] = (unsigned)bstar;
  }
}

// ---------------- phase 3: compact candidates (block-aggregated atomic) -----
__global__ void __launch_bounds__(256) k_compact(const float* __restrict__ in,
                                                 const unsigned* __restrict__ thr,
                                                 unsigned* __restrict__ cnt,
                                                 unsigned long long* __restrict__ cand) {
  __shared__ unsigned scnt, sbase;
  int b = blockIdx.x >> 8, sl = blockIdx.x & 255;
  if (threadIdx.x == 0) scnt = 0u;
  unsigned T = thr[b];
  const float* p = in + (size_t)b * 9 * HW;
  int base = sl * 1024 + threadIdx.x * 4;
  float4 v = *(const float4*)(p + base);
  float vv0 = v.x, vv1 = v.y, vv2 = v.z, vv3 = v.w;
  __syncthreads();
  bool c0 = (sortkey(vv0) >> 20) >= T;
  bool c1 = (sortkey(vv1) >> 20) >= T;
  bool c2 = (sortkey(vv2) >> 20) >= T;
  bool c3 = (sortkey(vv3) >> 20) >= T;
  int lc = (int)c0 + (int)c1 + (int)c2 + (int)c3;
  unsigned mypos = 0;
  if (lc) mypos = atomicAdd(&scnt, (unsigned)lc);
  __syncthreads();
  if (threadIdx.x == 0 && scnt) sbase = atomicAdd(&cnt[b * 32], scnt);
  __syncthreads();
  if (lc) {
    unsigned mybase = sbase + mypos;
    unsigned long long* dst = cand + (size_t)b * 4096;
    int o0 = 0, o1 = c0, o2 = o1 + c1, o3 = o2 + c2;
    if (c0 && mybase + o0 < 4096u) {
      unsigned long long k = ((unsigned long long)__float_as_uint(xla_sigmoid(vv0)) << 32) | (unsigned)(~(unsigned)(base + 0));
      dst[mybase + o0] = k;
    }
    if (c1 && mybase + o1 < 4096u) {
      unsigned long long k = ((unsigned long long)__float_as_uint(xla_sigmoid(vv1)) << 32) | (unsigned)(~(unsigned)(base + 1));
      dst[mybase + o1] = k;
    }
    if (c2 && mybase + o2 < 4096u) {
      unsigned long long k = ((unsigned long long)__float_as_uint(xla_sigmoid(vv2)) << 32) | (unsigned)(~(unsigned)(base + 2));
      dst[mybase + o2] = k;
    }
    if (c3 && mybase + o3 < 4096u) {
      unsigned long long k = ((unsigned long long)__float_as_uint(xla_sigmoid(vv3)) << 32) | (unsigned)(~(unsigned)(base + 3));
      dst[mybase + o3] = k;
    }
  }
}

// ---------------- phase 4: sort candidates, decode top-512 ------------------
__global__ void __launch_bounds__(1024) k_sortdecode(const float* __restrict__ in,
                                                     const unsigned* __restrict__ cnt,
                                                     const unsigned long long* __restrict__ cand,
                                                     float* __restrict__ boxes) {
  __shared__ unsigned long long s[4096];
  int b = blockIdx.x;
  unsigned n = cnt[b * 32]; if (n > 4096u) n = 4096u;
  int S = (n <= 2048u) ? 2048 : 4096;   // threshold-bin bound makes 2048 the norm
  for (int i = threadIdx.x; i < S; i += 1024)
    s[i] = (i < (int)n) ? cand[(size_t)b * 4096 + i] : 0ull;
  __syncthreads();
  // bitonic sort, descending (composite key: conf desc, then index asc)
  for (int k = 2; k <= S; k <<= 1) {
    for (int j = k >> 1; j > 0; j >>= 1) {
      for (int e = 0; e < S / 1024; e++) {
        int i = threadIdx.x + e * 1024;
        int ixj = i ^ j;
        if (ixj > i) {
          bool dirDesc = ((i & k) == 0);
          unsigned long long a = s[i], c = s[ixj];
          if ((a < c) == dirDesc) { s[i] = c; s[ixj] = a; }
        }
      }
      __syncthreads();
    }
  }
  int t = threadIdx.x;
  if (t < KTOP) {
    unsigned long long key = s[t];
    float* dst = boxes + ((size_t)b * KTOP + t) * 8;
    if ((unsigned)(key >> 32) == 0u) {   // impossible in practice; safety
      #pragma unroll
      for (int c = 0; c < 8; c++) dst[c] = 0.0f;
    } else {
      unsigned pix = ~(unsigned)(key & 0xffffffffull);
      float conf = __uint_as_float((unsigned)(key >> 32));
      const float* p = in + (size_t)b * 9 * HW;
      float o1 = p[1 * HW + pix], o2 = p[2 * HW + pix], o3 = p[3 * HW + pix];
      float o4 = p[4 * HW + pix], o5 = p[5 * HW + pix], o6 = p[6 * HW + pix];
      float o7 = p[7 * HW + pix], o8 = p[8 * HW + pix];
      float x = xla_sigmoid(o1) + (float)(pix & 511);
      float y = xla_sigmoid(o2) + (float)(pix >> 9);
      float z = xla_sigmoid(o3) * 4.0f;
      float l = expf(o4) * 3.9f;
      float w = expf(o5) * 1.6f;
      float h = expf(o6) * 1.56f;
      float yw = atan2f(tanhf(o7), tanhf(o8));
      dst[0] = conf; dst[1] = x; dst[2] = y; dst[3] = z;
      dst[4] = l; dst[5] = w; dst[6] = h; dst[7] = yw;
    }
  }
}

// ---------------- rotated-box IoU (fp32 mirror of the reference) ------------
#define CE_(I, J) {                                                         \
  bool sw_ = (ang[I] > ang[J]) || ((ang[I] == ang[J]) && (oi[I] > oi[J]));  \
  if (sw_) { float tf_; int ti_;                                            \
    tf_ = ang[I]; ang[I] = ang[J]; ang[J] = tf_;                            \
    ti_ = oi[I];  oi[I]  = oi[J];  oi[J]  = ti_;                            \
    tf_ = qx[I];  qx[I]  = qx[J];  qx[J]  = tf_;                            \
    tf_ = qy[I];  qy[I]  = qy[J];  qy[J]  = tf_; } }

#define MPASS(P, R, D)                                                      \
  _Pragma("unroll")                                                         \
  for (int i_ = 0; i_ < 32 - (D); i_++) {                                   \
    if ((i_ & (P)) == (R)) CE_(i_, i_ + (D));                               \
  }

__device__ float pair_iou3d(const float a[7], const float b[7]) {
  const float KLX[4] = {0.5f, 0.5f, -0.5f, -0.5f};
  const float KLY[4] = {0.5f, -0.5f, -0.5f, 0.5f};
  float cax[4], cay[4], cbx[4], cby[4];
  float cA = cosf(a[6]), sA = sinf(a[6]);
  float cB = cosf(b[6]), sB = sinf(b[6]);
  #pragma unroll
  for (int k = 0; k < 4; k++) {
    float lx = KLX[k] * a[3], ly = KLY[k] * a[4];
    cax[k] = a[0] + lx * cA - ly * sA;
    cay[k] = a[1] + lx * sA + ly * cA;
    lx = KLX[k] * b[3]; ly = KLY[k] * b[4];
    cbx[k] = b[0] + lx * cB - ly * sB;
    cby[k] = b[1] + lx * sB + ly * cB;
  }
  float px[24], py[24]; bool val[24];
  #pragma unroll
  for (int ai = 0; ai < 4; ai++) {
    float a1x = cax[ai], a1y = cay[ai];
    float rx = cax[(ai + 1) & 3] - a1x, ry = cay[(ai + 1) & 3] - a1y;
    #pragma unroll
    for (int bj = 0; bj < 4; bj++) {
      float b1x = cbx[bj], b1y = cby[bj];
      float sx = cbx[(bj + 1) & 3] - b1x, sy = cby[(bj + 1) & 3] - b1y;
      float qpx = b1x - a1x, qpy = b1y - a1y;
      float den = rx * sy - ry * sx;
      bool dok = fabsf(den) > 1e-8f;
      float safe = dok ? den : 1.0f;
      float t = (qpx * sy - qpy * sx) / safe;
      float u = (qpx * ry - qpy * rx) / safe;
      bool ok = dok && (t >= 0.0f) && (t <= 1.0f) && (u >= 0.0f) && (u <= 1.0f);
      px[ai * 4 + bj] = a1x + t * rx;
      py[ai * 4 + bj] = a1y + t * ry;
      val[ai * 4 + bj] = ok;
    }
  }
  #pragma unroll
  for (int k = 0; k < 4; k++) {
    px[16 + k] = cax[k]; py[16 + k] = cay[k];
    { float dx = cax[k] - b[0], dy = cay[k] - b[1];
      float lx = dx * cB + dy * sB, ly = -dx * sB + dy * cB;
      val[16 + k] = (fabsf(lx) <= b[3] * 0.5f + 1e-6f) &&
                    (fabsf(ly) <= b[4] * 0.5f + 1e-6f); }
    px[20 + k] = cbx[k]; py[20 + k] = cby[k];
    { float dx = cbx[k] - a[0], dy = cby[k] - a[1];
      float lx = dx * cA + dy * sA, ly = -dx * sA + dy * cA;
      val[20 + k] = (fabsf(lx) <= a[3] * 0.5f + 1e-6f) &&
                    (fabsf(ly) <= a[4] * 0.5f + 1e-6f); }
  }
  float n = 0.0f, sxs = 0.0f, sys = 0.0f;
  #pragma unroll
  for (int k = 0; k < 24; k++) {
    float vf = val[k] ? 1.0f : 0.0f;
    n += vf; sxs += px[k] * vf; sys += py[k] * vf;
  }
  float inv = fmaxf(n, 1.0f);
  float ctrx = sxs / inv, ctry = sys / inv;
  float fx = px[0], fy = py[0]; bool found = false;
  #pragma unroll
  for (int k = 0; k < 24; k++) {           // fill = pts[argmax(val)] = first valid
    bool take = val[k] && !found;
    if (take) { fx = px[k]; fy = py[k]; }
    found = found || val[k];
  }
  float ang[32], qx[32], qy[32]; int oi[32];
  #pragma unroll
  for (int k = 0; k < 24; k++) {
    float X = val[k] ? px[k] : fx, Y = val[k] ? py[k] : fy;
    qx[k] = X; qy[k] = Y; oi[k] = k;
    ang[k] = atan2f(Y - ctry, X - ctrx);
  }
  #pragma unroll
  for (int k = 24; k < 32; k++) {
    qx[k] = 0.0f; qy[k] = 0.0f; oi[k] = k;
    ang[k] = __int_as_float(0x7f800000);   // +inf pads sink to the end
  }
  MPASS(16, 0, 16);
  MPASS(8, 0, 8);  MPASS(8, 8, 8);
  MPASS(4, 0, 4);  MPASS(4, 4, 12); MPASS(4, 4, 4);
  MPASS(2, 0, 2);  MPASS(2, 2, 14); MPASS(2, 2, 6);  MPASS(2, 2, 2);
  MPASS(1, 0, 1);  MPASS(1, 1, 15); MPASS(1, 1, 7);  MPASS(1, 1, 3); MPASS(1, 1, 1);
  float area2 = 0.0f;
  #pragma unroll
  for (int k = 0; k < 24; k++) {
    int k2 = (k + 1) % 24;
    float x1 = qx[k] - ctrx, y1 = qy[k] - ctry;
    float x2 = qx[k2] - ctrx, y2 = qy[k2] - ctry;
    area2 += x1 * y2 - y1 * x2;
  }
  float area = 0.5f * fabsf(area2);
  if (!(n >= 3.0f)) area = 0.0f;
  float z1 = fmaxf(a[2] - a[5] * 0.5f, b[2] - b[5] * 0.5f);
  float z2 = fminf(a[2] + a[5] * 0.5f, b[2] + b[5] * 0.5f);
  float inter = area * fmaxf(z2 - z1, 0.0f);
  float va = a[3] * a[4] * a[5], vb = b[3] * b[4] * b[5];
  return inter / (va + vb - inter + 1e-8f);
}

// ---------------- phase 5: suppression bit-matrix (j > i only) --------------
__global__ void __launch_bounds__(256) k_iou(const float* __restrict__ boxes,
                                             unsigned long long* __restrict__ sup,
                                             unsigned long long* __restrict__ rowAny) {
  int bi_ = blockIdx.x;
  int b = bi_ >> 9, i = bi_ & 511;
  const float* A = boxes + ((size_t)b * KTOP + i) * 8;
  if (A[0] <= 0.5f) return;            // row i can never suppress (uniform branch)
  float a7[7];
  #pragma unroll
  for (int c = 0; c < 7; c++) a7[c] = A[1 + c];
  float ra = 0.5f * sqrtf(a7[3] * a7[3] + a7[4] * a7[4]);
  float az1 = a7[2] - a7[5] * 0.5f, az2 = a7[2] + a7[5] * 0.5f;
  for (int j = i + 1 + threadIdx.x; j < KTOP; j += 256) {
    const float* Bp = boxes + ((size_t)b * KTOP + j) * 8;
    float b7[7];
    #pragma unroll
    for (int c = 0; c < 7; c++) b7[c] = Bp[1 + c];
    float dx = b7[0] - a7[0], dy = b7[1] - a7[1];
    float rb = 0.5f * sqrtf(b7[3] * b7[3] + b7[4] * b7[4]);
    float rs = (ra + rb) * 1.001f + 0.01f;     // disjoint circles => IoU == 0
    if (dx * dx + dy * dy > rs * rs) continue;
    float z1 = fmaxf(az1, b7[2] - b7[5] * 0.5f);
    float z2 = fminf(az2, b7[2] + b7[5] * 0.5f);
    if (!(z2 - z1 > 0.0f)) continue;           // inter = area*max(dz,0) = 0
    float iou = pair_iou3d(a7, b7);
    if (iou > 0.1f) {
      atomicOr(&sup[((size_t)b * KTOP + i) * 8 + (j >> 6)], 1ull << (j & 63));
      atomicOr(&rowAny[b * 8 + (i >> 6)], 1ull << (i & 63));
    }
  }
}

// ---------------- phase 6: sequential NMS on bitmasks + output --------------
__global__ void __launch_bounds__(512) k_nms_out(const float* __restrict__ boxes,
                                                 const unsigned long long* __restrict__ sup,
                                                 const unsigned long long* __restrict__ rowAny,
                                                 float* __restrict__ out) {
  int b = blockIdx.x, t = threadIdx.x;
  __shared__ unsigned long long kw[8];
  float conf = boxes[((size_t)b * KTOP + t) * 8];
  unsigned long long m = __ballot(conf > 0.5f);
  if ((t & 63) == 0) kw[t >> 6] = m;
  __syncthreads();
  if (t == 0) {
    unsigned long long kp[8];
    #pragma unroll
    for (int w = 0; w < 8; w++) kp[w] = kw[w];
    unsigned long long anyw[8];
    #pragma unroll
    for (int w = 0; w < 8; w++) anyw[w] = rowAny[b * 8 + w];
    #pragma unroll
    for (int w = 0; w < 8; w++) {
      unsigned long long act = kp[w] & anyw[w];
      while (act) {
        int bit = __ffsll(act) - 1;
        act &= act - 1;
        const unsigned long long* row = sup + ((size_t)b * KTOP + (w * 64 + bit)) * 8;
        #pragma unroll
        for (int u = 0; u < 8; u++) kp[u] &= ~row[u];   // row has only bits j>i
        act &= kp[w];     // suppression may have cleared later bits in this word
      }
    }
    #pragma unroll
    for (int w = 0; w < 8; w++) kw[w] = kp[w];
  }
  __syncthreads();
  bool kept = (kw[t >> 6] >> (t & 63)) & 1ull;
  const float* src = boxes + ((size_t)b * KTOP + t) * 8;
  float* dst = out + ((size_t)b * KTOP + t) * 8;
  #pragma unroll
  for (int c = 0; c < 8; c++) dst[c] = kept ? src[c] : 0.0f;
}

extern "C" void kernel_launch(void* const* d_in, const int* in_sizes, int n_in,
                              void* d_out, int out_size, void* d_ws, size_t ws_size,
                              hipStream_t stream) {
  const float* in = (const float*)d_in[0];   // (8, 9, 512, 512) f32
  float* out = (float*)d_out;                // (8, 512, 8) f32
  char* ws = (char*)d_ws;
  unsigned* hist = (unsigned*)(ws + OFF_HIST);
  unsigned long long* cand = (unsigned long long*)(ws + OFF_CAND); // aliases hist (hist dead after k_thresh)
  unsigned* cnt = (unsigned*)(ws + OFF_CNT);
  unsigned* thr = (unsigned*)(ws + OFF_THR);
  unsigned long long* rowAny = (unsigned long long*)(ws + OFF_ANY);
  unsigned long long* sup = (unsigned long long*)(ws + OFF_SUP);
  float* boxes = (float*)(ws + OFF_BOX);

  hipMemsetAsync(d_ws, 0, ZERO_BYTES, stream);
  k_hist<<<dim3(2048), dim3(256), 0, stream>>>(in, hist);
  k_thresh<<<dim3(8), dim3(64), 0, stream>>>(hist, thr);
  k_compact<<<dim3(2048), dim3(256), 0, stream>>>(in, thr, cnt, cand);
  k_sortdecode<<<dim3(8), dim3(1024), 0, stream>>>(in, cnt, cand, boxes);
  k_iou<<<dim3(8 * KTOP), dim3(256), 0, stream>>>(boxes, sup, rowAny);
  k_nms_out<<<dim3(8), dim3(512), 0, stream>>>(boxes, sup, rowAny, out);
}